// Round 4
// baseline (332.394 us; speedup 1.0000x reference)
//
#include <hip/hip_runtime.h>
#include <hip/hip_fp16.h>

// WHTConv2D fused single-kernel: out = Rw(Rh(g(Rh(Rw(x))))) + x
//   Rw/Rh = normalized FWHT-256 along w/h (separable; order swapped vs ref, exact)
//   g(f)[h,w] = sum_p tanh(f*v_p) * relu(|f*v_p| - |T_p|)
// x: (8,64,256,256) f32 -> 512 planes of 256x256. One block per plane, whole
// plane staged in LDS as fp16 (128 KB). v,T: (4,256,256) f32, L2-resident.
//
// Round-4 change: pin amdgpu_waves_per_eu(4,4). launch_bounds(1024,4) was a
// no-op (VGPR stayed 64 = the 8-waves/EU max-occupancy target; f[4][16]
// spilled: +434 MB scratch writes, VALUBusy 20%). LDS caps us at 1 block/CU
// = 4 waves/EU anyway, so a 128-VGPR budget is free.

#define NPX 65536   // pixels per plane
#define SC  0.0625f // 1/sqrt(256)

__device__ __forceinline__ unsigned int h2u(__half2 h) {
  union { __half2 h; unsigned int u; } c; c.h = h; return c.u;
}
__device__ __forceinline__ __half2 u2h(unsigned int u) {
  union { __half2 h; unsigned int u; } c; c.u = u; return c.h;
}

// 16-point unnormalized FWHT fully in registers.
__device__ __forceinline__ void fwht16(float f[16]) {
  #pragma unroll
  for (int d = 1; d < 16; d <<= 1) {
    #pragma unroll
    for (int i = 0; i < 16; ++i) {
      if (!(i & d)) {
        float a = f[i], b = f[i | d];
        f[i]     = a + b;
        f[i | d] = a - b;
      }
    }
  }
}

// 256-point unnormalized FWHT across one wave; lane holds elems i = 4*lane + j.
__device__ __forceinline__ void fwht256_wave(float r[4], int lane) {
  float a0 = r[0] + r[1], b0 = r[0] - r[1];
  float a1 = r[2] + r[3], b1 = r[2] - r[3];
  r[0] = a0 + a1; r[1] = b0 + b1; r[2] = a0 - a1; r[3] = b0 - b1;
  #pragma unroll
  for (int m = 1; m <= 32; m <<= 1) {
    const float s = (lane & m) ? -1.0f : 1.0f;
    #pragma unroll
    for (int j = 0; j < 4; ++j) {
      float t = __shfl_xor(r[j], m);
      r[j] = fmaf(r[j], s, t);   // low lane: r+t ; high lane: t-r
    }
  }
}

// one term of g: tanh(a) * relu(|a| - |T|)
__device__ __forceinline__ float g_term(float a, float absT) {
  float ax = fabsf(a);
  float rl = fmaxf(ax - absT, 0.0f);
  float e  = __builtin_amdgcn_exp2f(ax * 2.8853900817779268f); // exp(2ax)
  float th = 1.0f - 2.0f * __builtin_amdgcn_rcpf(e + 1.0f);    // tanh(ax)
  return copysignf(th, a) * rl;
}

__global__ __attribute__((amdgpu_flat_work_group_size(1024, 1024),
                          amdgpu_waves_per_eu(4, 4)))
void k_fused(const float* __restrict__ x,
             const float* __restrict__ v,
             const float* __restrict__ T,
             float* __restrict__ out) {
  extern __shared__ __half S[];            // [256][256] fp16, pitch 256
  const int tid  = threadIdx.x;
  const int lane = tid & 63;
  const int wv   = tid >> 6;               // wave id 0..15
  const size_t pbase = (size_t)blockIdx.x * NPX;

  // ---- phase 1: row FWHT of x -> LDS (fp16, x SC) ----
  // wave wv owns rows 16*wv .. 16*wv+15; all LDS ops have wave-uniform row.
  for (int rr = 0; rr < 16; ++rr) {
    const int row = wv * 16 + rr;
    const float4 xv = *reinterpret_cast<const float4*>(x + pbase + (size_t)row * 256 + 4 * lane);
    float r[4] = {xv.x, xv.y, xv.z, xv.w};
    fwht256_wave(r, lane);
    uint2 pk;
    pk.x = h2u(__floats2half2_rn(r[0] * SC, r[1] * SC));
    pk.y = h2u(__floats2half2_rn(r[2] * SC, r[3] * SC));
    *reinterpret_cast<uint2*>(&S[row * 256 + 4 * lane]) = pk;
  }
  __syncthreads();

  // ---- phase 2: column Rh o g o Rh, radix-16 (h = 16a + k) ----
  // thread (q,g): cols 4q..4q+3, q = tid&63 (wave-uniform g => wave-uniform h).
  const int q = tid & 63;
  const int g = tid >> 6;
  float f[4][16];

  // pass A: FWHT16 over k (contiguous rows 16g+k)
  #pragma unroll
  for (int k = 0; k < 16; ++k) {
    uint2 d = *reinterpret_cast<uint2*>(&S[(16 * g + k) * 256 + 4 * q]);
    float2 lo = __half22float2(u2h(d.x));
    float2 hi = __half22float2(u2h(d.y));
    f[0][k] = lo.x; f[1][k] = lo.y; f[2][k] = hi.x; f[3][k] = hi.y;
  }
  #pragma unroll
  for (int c = 0; c < 4; ++c) fwht16(f[c]);
  #pragma unroll
  for (int k = 0; k < 16; ++k) {
    uint2 d;
    d.x = h2u(__floats2half2_rn(f[0][k], f[1][k]));
    d.y = h2u(__floats2half2_rn(f[2][k], f[3][k]));
    *reinterpret_cast<uint2*>(&S[(16 * g + k) * 256 + 4 * q]) = d;
  }
  __syncthreads();

  // pass B: FWHT16 over a (rows g+16a) -> xSC (f2 done) -> g -> FWHT16 over a -> xSC
  #pragma unroll
  for (int a = 0; a < 16; ++a) {
    uint2 d = *reinterpret_cast<uint2*>(&S[(g + 16 * a) * 256 + 4 * q]);
    float2 lo = __half22float2(u2h(d.x));
    float2 hi = __half22float2(u2h(d.y));
    f[0][a] = lo.x; f[1][a] = lo.y; f[2][a] = hi.x; f[3][a] = hi.y;
  }
  #pragma unroll
  for (int c = 0; c < 4; ++c) fwht16(f[c]);
  #pragma unroll
  for (int c = 0; c < 4; ++c)
    #pragma unroll
    for (int a = 0; a < 16; ++a) f[c][a] *= SC;

  #pragma unroll
  for (int a = 0; a < 16; ++a) {
    const size_t off = (size_t)(g + 16 * a) * 256 + 4 * q;
    float acc0 = 0.f, acc1 = 0.f, acc2 = 0.f, acc3 = 0.f;
    #pragma unroll
    for (int p = 0; p < 4; ++p) {
      const float4 vv = *reinterpret_cast<const float4*>(v + (size_t)p * NPX + off);
      const float4 tt = *reinterpret_cast<const float4*>(T + (size_t)p * NPX + off);
      acc0 += g_term(f[0][a] * vv.x, fabsf(tt.x));
      acc1 += g_term(f[1][a] * vv.y, fabsf(tt.y));
      acc2 += g_term(f[2][a] * vv.z, fabsf(tt.z));
      acc3 += g_term(f[3][a] * vv.w, fabsf(tt.w));
    }
    f[0][a] = acc0; f[1][a] = acc1; f[2][a] = acc2; f[3][a] = acc3;
  }
  #pragma unroll
  for (int c = 0; c < 4; ++c) fwht16(f[c]);   // Rh2 pass over a
  #pragma unroll
  for (int c = 0; c < 4; ++c)
    #pragma unroll
    for (int a = 0; a < 16; ++a) f[c][a] *= SC;
  #pragma unroll
  for (int a = 0; a < 16; ++a) {
    uint2 d;
    d.x = h2u(__floats2half2_rn(f[0][a], f[1][a]));
    d.y = h2u(__floats2half2_rn(f[2][a], f[3][a]));
    *reinterpret_cast<uint2*>(&S[(g + 16 * a) * 256 + 4 * q]) = d;
  }
  __syncthreads();

  // pass C: FWHT16 over k (Rh2 second half; scale already applied)
  #pragma unroll
  for (int k = 0; k < 16; ++k) {
    uint2 d = *reinterpret_cast<uint2*>(&S[(16 * g + k) * 256 + 4 * q]);
    float2 lo = __half22float2(u2h(d.x));
    float2 hi = __half22float2(u2h(d.y));
    f[0][k] = lo.x; f[1][k] = lo.y; f[2][k] = hi.x; f[3][k] = hi.y;
  }
  #pragma unroll
  for (int c = 0; c < 4; ++c) fwht16(f[c]);
  #pragma unroll
  for (int k = 0; k < 16; ++k) {
    uint2 d;
    d.x = h2u(__floats2half2_rn(f[0][k], f[1][k]));
    d.y = h2u(__floats2half2_rn(f[2][k], f[3][k]));
    *reinterpret_cast<uint2*>(&S[(16 * g + k) * 256 + 4 * q]) = d;
  }
  __syncthreads();

  // ---- phase 3: row FWHT (x SC) + x residual -> out ----
  for (int rr = 0; rr < 16; ++rr) {
    const int row = wv * 16 + rr;
    uint2 pk = *reinterpret_cast<uint2*>(&S[row * 256 + 4 * lane]);
    float2 lo = __half22float2(u2h(pk.x));
    float2 hi = __half22float2(u2h(pk.y));
    float r[4] = {lo.x, lo.y, hi.x, hi.y};
    fwht256_wave(r, lane);
    const float4 xv = *reinterpret_cast<const float4*>(x + pbase + (size_t)row * 256 + 4 * lane);
    float4 o;
    o.x = fmaf(r[0], SC, xv.x);
    o.y = fmaf(r[1], SC, xv.y);
    o.z = fmaf(r[2], SC, xv.z);
    o.w = fmaf(r[3], SC, xv.w);
    *reinterpret_cast<float4*>(out + pbase + (size_t)row * 256 + 4 * lane) = o;
  }
}

extern "C" void kernel_launch(void* const* d_in, const int* in_sizes, int n_in,
                              void* d_out, int out_size, void* d_ws, size_t ws_size,
                              hipStream_t stream) {
  const float* x = (const float*)d_in[0];
  const float* v = (const float*)d_in[1];
  const float* T = (const float*)d_in[2];
  float* out = (float*)d_out;

  const int lds_bytes = 256 * 256 * (int)sizeof(__half);   // 128 KiB
  (void)hipFuncSetAttribute(reinterpret_cast<const void*>(k_fused),
                            hipFuncAttributeMaxDynamicSharedMemorySize, lds_bytes);
  k_fused<<<512, 1024, lds_bytes, stream>>>(x, v, T, out);
}

// Round 5
// 322.241 us; speedup vs baseline: 1.0315x; 1.0315x over previous
//
#include <hip/hip_runtime.h>
#include <hip/hip_fp16.h>

// WHTConv2D fused single-kernel: out = Rw(Rh(g(Rh(Rw(x))))) + x
//   Rw/Rh = normalized FWHT-256 along w/h (separable; order swapped vs ref, exact)
//   g(f)[h,w] = sum_p tanh(f*v_p) * relu(|f*v_p| - |T_p|)
// x: (8,64,256,256) f32 -> 512 planes of 256x256. One block per plane, whole
// plane staged in LDS as fp16 (128 KB STATIC). v,T: (4,256,256) f32, L2/L3-resident.
//
// Round-5 change: static __shared__ (was dynamic extern __shared__). With
// dynamic LDS the compiler assumes LDS=0, targets 8 waves/EU, pins VGPR=64,
// and spills f[4][16] (+430 MB scratch writes, VALUBusy 20%). Static 128 KB
// makes the LDS occupancy cap visible: 1 block/CU -> 4 waves/EU -> 128-VGPR
// budget (round-1 k_col precedent: static 36 KB -> VGPR=128, no spill).

#define NPX 65536   // pixels per plane
#define SC  0.0625f // 1/sqrt(256)

__device__ __forceinline__ unsigned int h2u(__half2 h) {
  union { __half2 h; unsigned int u; } c; c.h = h; return c.u;
}
__device__ __forceinline__ __half2 u2h(unsigned int u) {
  union { __half2 h; unsigned int u; } c; c.u = u; return c.h;
}

// 16-point unnormalized FWHT fully in registers.
__device__ __forceinline__ void fwht16(float f[16]) {
  #pragma unroll
  for (int d = 1; d < 16; d <<= 1) {
    #pragma unroll
    for (int i = 0; i < 16; ++i) {
      if (!(i & d)) {
        float a = f[i], b = f[i | d];
        f[i]     = a + b;
        f[i | d] = a - b;
      }
    }
  }
}

// 256-point unnormalized FWHT across one wave; lane holds elems i = 4*lane + j.
__device__ __forceinline__ void fwht256_wave(float r[4], int lane) {
  float a0 = r[0] + r[1], b0 = r[0] - r[1];
  float a1 = r[2] + r[3], b1 = r[2] - r[3];
  r[0] = a0 + a1; r[1] = b0 + b1; r[2] = a0 - a1; r[3] = b0 - b1;
  #pragma unroll
  for (int m = 1; m <= 32; m <<= 1) {
    const float s = (lane & m) ? -1.0f : 1.0f;
    #pragma unroll
    for (int j = 0; j < 4; ++j) {
      float t = __shfl_xor(r[j], m);
      r[j] = fmaf(r[j], s, t);   // low lane: r+t ; high lane: t-r
    }
  }
}

// one term of g: tanh(a) * relu(|a| - |T|)
__device__ __forceinline__ float g_term(float a, float absT) {
  float ax = fabsf(a);
  float rl = fmaxf(ax - absT, 0.0f);
  float e  = __builtin_amdgcn_exp2f(ax * 2.8853900817779268f); // exp(2ax)
  float th = 1.0f - 2.0f * __builtin_amdgcn_rcpf(e + 1.0f);    // tanh(ax)
  return copysignf(th, a) * rl;
}

__global__ __attribute__((amdgpu_flat_work_group_size(1024, 1024),
                          amdgpu_waves_per_eu(4, 4)))
void k_fused(const float* __restrict__ x,
             const float* __restrict__ v,
             const float* __restrict__ T,
             float* __restrict__ out) {
  __shared__ __half S[256 * 256];          // 128 KiB static, pitch 256
  const int tid  = threadIdx.x;
  const int lane = tid & 63;
  const int wv   = tid >> 6;               // wave id 0..15
  const size_t pbase = (size_t)blockIdx.x * NPX;

  // ---- phase 1: row FWHT of x -> LDS (fp16, x SC) ----
  // wave wv owns rows 16*wv .. 16*wv+15; all LDS ops have wave-uniform row.
  for (int rr = 0; rr < 16; ++rr) {
    const int row = wv * 16 + rr;
    const float4 xv = *reinterpret_cast<const float4*>(x + pbase + (size_t)row * 256 + 4 * lane);
    float r[4] = {xv.x, xv.y, xv.z, xv.w};
    fwht256_wave(r, lane);
    uint2 pk;
    pk.x = h2u(__floats2half2_rn(r[0] * SC, r[1] * SC));
    pk.y = h2u(__floats2half2_rn(r[2] * SC, r[3] * SC));
    *reinterpret_cast<uint2*>(&S[row * 256 + 4 * lane]) = pk;
  }
  __syncthreads();

  // ---- phase 2: column Rh o g o Rh, radix-16 (h = 16a + k) ----
  // thread (q,g): cols 4q..4q+3, q = tid&63 (wave-uniform g => wave-uniform h).
  const int q = tid & 63;
  const int g = tid >> 6;
  float f[4][16];

  // pass A: FWHT16 over k (contiguous rows 16g+k)
  #pragma unroll
  for (int k = 0; k < 16; ++k) {
    uint2 d = *reinterpret_cast<uint2*>(&S[(16 * g + k) * 256 + 4 * q]);
    float2 lo = __half22float2(u2h(d.x));
    float2 hi = __half22float2(u2h(d.y));
    f[0][k] = lo.x; f[1][k] = lo.y; f[2][k] = hi.x; f[3][k] = hi.y;
  }
  #pragma unroll
  for (int c = 0; c < 4; ++c) fwht16(f[c]);
  #pragma unroll
  for (int k = 0; k < 16; ++k) {
    uint2 d;
    d.x = h2u(__floats2half2_rn(f[0][k], f[1][k]));
    d.y = h2u(__floats2half2_rn(f[2][k], f[3][k]));
    *reinterpret_cast<uint2*>(&S[(16 * g + k) * 256 + 4 * q]) = d;
  }
  __syncthreads();

  // pass B: FWHT16 over a (rows g+16a) -> xSC (f2 done) -> g -> FWHT16 over a -> xSC
  #pragma unroll
  for (int a = 0; a < 16; ++a) {
    uint2 d = *reinterpret_cast<uint2*>(&S[(g + 16 * a) * 256 + 4 * q]);
    float2 lo = __half22float2(u2h(d.x));
    float2 hi = __half22float2(u2h(d.y));
    f[0][a] = lo.x; f[1][a] = lo.y; f[2][a] = hi.x; f[3][a] = hi.y;
  }
  #pragma unroll
  for (int c = 0; c < 4; ++c) fwht16(f[c]);
  #pragma unroll
  for (int c = 0; c < 4; ++c)
    #pragma unroll
    for (int a = 0; a < 16; ++a) f[c][a] *= SC;

  #pragma unroll
  for (int a = 0; a < 16; ++a) {
    const size_t off = (size_t)(g + 16 * a) * 256 + 4 * q;
    float acc0 = 0.f, acc1 = 0.f, acc2 = 0.f, acc3 = 0.f;
    #pragma unroll
    for (int p = 0; p < 4; ++p) {
      const float4 vv = *reinterpret_cast<const float4*>(v + (size_t)p * NPX + off);
      const float4 tt = *reinterpret_cast<const float4*>(T + (size_t)p * NPX + off);
      acc0 += g_term(f[0][a] * vv.x, fabsf(tt.x));
      acc1 += g_term(f[1][a] * vv.y, fabsf(tt.y));
      acc2 += g_term(f[2][a] * vv.z, fabsf(tt.z));
      acc3 += g_term(f[3][a] * vv.w, fabsf(tt.w));
    }
    f[0][a] = acc0; f[1][a] = acc1; f[2][a] = acc2; f[3][a] = acc3;
  }
  #pragma unroll
  for (int c = 0; c < 4; ++c) fwht16(f[c]);   // Rh2 pass over a
  #pragma unroll
  for (int c = 0; c < 4; ++c)
    #pragma unroll
    for (int a = 0; a < 16; ++a) f[c][a] *= SC;
  #pragma unroll
  for (int a = 0; a < 16; ++a) {
    uint2 d;
    d.x = h2u(__floats2half2_rn(f[0][a], f[1][a]));
    d.y = h2u(__floats2half2_rn(f[2][a], f[3][a]));
    *reinterpret_cast<uint2*>(&S[(g + 16 * a) * 256 + 4 * q]) = d;
  }
  __syncthreads();

  // pass C: FWHT16 over k (Rh2 second half; scale already applied)
  #pragma unroll
  for (int k = 0; k < 16; ++k) {
    uint2 d = *reinterpret_cast<uint2*>(&S[(16 * g + k) * 256 + 4 * q]);
    float2 lo = __half22float2(u2h(d.x));
    float2 hi = __half22float2(u2h(d.y));
    f[0][k] = lo.x; f[1][k] = lo.y; f[2][k] = hi.x; f[3][k] = hi.y;
  }
  #pragma unroll
  for (int c = 0; c < 4; ++c) fwht16(f[c]);
  #pragma unroll
  for (int k = 0; k < 16; ++k) {
    uint2 d;
    d.x = h2u(__floats2half2_rn(f[0][k], f[1][k]));
    d.y = h2u(__floats2half2_rn(f[2][k], f[3][k]));
    *reinterpret_cast<uint2*>(&S[(16 * g + k) * 256 + 4 * q]) = d;
  }
  __syncthreads();

  // ---- phase 3: row FWHT (x SC) + x residual -> out ----
  for (int rr = 0; rr < 16; ++rr) {
    const int row = wv * 16 + rr;
    uint2 pk = *reinterpret_cast<uint2*>(&S[row * 256 + 4 * lane]);
    float2 lo = __half22float2(u2h(pk.x));
    float2 hi = __half22float2(u2h(pk.y));
    float r[4] = {lo.x, lo.y, hi.x, hi.y};
    fwht256_wave(r, lane);
    const float4 xv = *reinterpret_cast<const float4*>(x + pbase + (size_t)row * 256 + 4 * lane);
    float4 o;
    o.x = fmaf(r[0], SC, xv.x);
    o.y = fmaf(r[1], SC, xv.y);
    o.z = fmaf(r[2], SC, xv.z);
    o.w = fmaf(r[3], SC, xv.w);
    *reinterpret_cast<float4*>(out + pbase + (size_t)row * 256 + 4 * lane) = o;
  }
}

extern "C" void kernel_launch(void* const* d_in, const int* in_sizes, int n_in,
                              void* d_out, int out_size, void* d_ws, size_t ws_size,
                              hipStream_t stream) {
  const float* x = (const float*)d_in[0];
  const float* v = (const float*)d_in[1];
  const float* T = (const float*)d_in[2];
  float* out = (float*)d_out;

  k_fused<<<512, 1024, 0, stream>>>(x, v, T, out);
}

// Round 6
// 238.585 us; speedup vs baseline: 1.3932x; 1.3506x over previous
//
#include <hip/hip_runtime.h>
#include <hip/hip_fp16.h>

// WHTConv2D fused single-kernel: out = Rw(Rh(g(Rh(Rw(x))))) + x
//   Rw/Rh = normalized FWHT-256 along w/h (separable; order swapped vs ref, exact)
//   g(f)[h,w] = sum_p tanh(f*v_p) * relu(|f*v_p| - |T_p|)
// x: (8,64,256,256) f32 -> 512 planes of 256x256. One block per plane, whole
// plane staged in LDS as fp16 (128 KB static). v,T: (4,256,256) f32, L2-resident.
//
// Round-6 change: the allocator pins 1024-thread kernels at 64 VGPRs no matter
// what (launch_bounds/waves_per_eu/static-LDS all failed to move it), so the
// column phase is restructured to FIT 64 VGPRs: two half-sweeps (unroll 1),
// each with f[2][16]=32 floats of state (cols 2q+128h, 2q+128h+1), b32 LDS
// accesses (bank = q%32 -> 2 lanes/bank = free), float2 v/T loads (contiguous
// 512 B/wave). Same math; spill (+430 MB scratch writes, VALUBusy 20%) gone.

#define NPX 65536   // pixels per plane
#define SC  0.0625f // 1/sqrt(256)

__device__ __forceinline__ unsigned int h2u(__half2 h) {
  union { __half2 h; unsigned int u; } c; c.h = h; return c.u;
}
__device__ __forceinline__ __half2 u2h(unsigned int u) {
  union { __half2 h; unsigned int u; } c; c.u = u; return c.h;
}

// 16-point unnormalized FWHT fully in registers.
__device__ __forceinline__ void fwht16(float f[16]) {
  #pragma unroll
  for (int d = 1; d < 16; d <<= 1) {
    #pragma unroll
    for (int i = 0; i < 16; ++i) {
      if (!(i & d)) {
        float a = f[i], b = f[i | d];
        f[i]     = a + b;
        f[i | d] = a - b;
      }
    }
  }
}

// 256-point unnormalized FWHT across one wave; lane holds elems i = 4*lane + j.
__device__ __forceinline__ void fwht256_wave(float r[4], int lane) {
  float a0 = r[0] + r[1], b0 = r[0] - r[1];
  float a1 = r[2] + r[3], b1 = r[2] - r[3];
  r[0] = a0 + a1; r[1] = b0 + b1; r[2] = a0 - a1; r[3] = b0 - b1;
  #pragma unroll
  for (int m = 1; m <= 32; m <<= 1) {
    const float s = (lane & m) ? -1.0f : 1.0f;
    #pragma unroll
    for (int j = 0; j < 4; ++j) {
      float t = __shfl_xor(r[j], m);
      r[j] = fmaf(r[j], s, t);   // low lane: r+t ; high lane: t-r
    }
  }
}

// one term of g: tanh(a) * relu(|a| - |T|)
__device__ __forceinline__ float g_term(float a, float absT) {
  float ax = fabsf(a);
  float rl = fmaxf(ax - absT, 0.0f);
  float e  = __builtin_amdgcn_exp2f(ax * 2.8853900817779268f); // exp(2ax)
  float th = 1.0f - 2.0f * __builtin_amdgcn_rcpf(e + 1.0f);    // tanh(ax)
  return copysignf(th, a) * rl;
}

__global__ __launch_bounds__(1024) void k_fused(const float* __restrict__ x,
                                                const float* __restrict__ v,
                                                const float* __restrict__ T,
                                                float* __restrict__ out) {
  __shared__ __half S[256 * 256];          // 128 KiB static, pitch 256
  const int tid  = threadIdx.x;
  const int lane = tid & 63;
  const int wv   = tid >> 6;               // wave id 0..15
  const size_t pbase = (size_t)blockIdx.x * NPX;

  // ---- phase 1: row FWHT of x -> LDS (fp16, x SC) ----
  #pragma unroll 2
  for (int rr = 0; rr < 16; ++rr) {
    const int row = wv * 16 + rr;
    const float4 xv = *reinterpret_cast<const float4*>(x + pbase + (size_t)row * 256 + 4 * lane);
    float r[4] = {xv.x, xv.y, xv.z, xv.w};
    fwht256_wave(r, lane);
    uint2 pk;
    pk.x = h2u(__floats2half2_rn(r[0] * SC, r[1] * SC));
    pk.y = h2u(__floats2half2_rn(r[2] * SC, r[3] * SC));
    *reinterpret_cast<uint2*>(&S[row * 256 + 4 * lane]) = pk;
  }
  __syncthreads();

  // ---- phase 2: column Rh o g o Rh, radix-16 (h = 16a + k) ----
  // Two half-sweeps (unroll 1!): sweep hs owns cols cb=2q+128*hs, cb+1.
  // q = tid&63 (wave-uniform g => wave-uniform row in every LDS access).
  const int q = tid & 63;
  const int g = tid >> 6;
  float f[2][16];

  // pass A: FWHT16 over k (contiguous rows 16g+k)
  #pragma unroll 1
  for (int hs = 0; hs < 2; ++hs) {
    const int cb = 2 * q + 128 * hs;
    #pragma unroll
    for (int k = 0; k < 16; ++k) {
      unsigned int d = *reinterpret_cast<unsigned int*>(&S[(16 * g + k) * 256 + cb]);
      float2 e = __half22float2(u2h(d));
      f[0][k] = e.x; f[1][k] = e.y;
    }
    fwht16(f[0]); fwht16(f[1]);
    #pragma unroll
    for (int k = 0; k < 16; ++k) {
      *reinterpret_cast<unsigned int*>(&S[(16 * g + k) * 256 + cb]) =
          h2u(__floats2half2_rn(f[0][k], f[1][k]));
    }
  }
  __syncthreads();

  // pass B: rows g+16a: FWHT16 over a (completes Rh1) -> xSC -> g -> FWHT16
  // over a (first half of Rh2) -> xSC -> back to LDS
  #pragma unroll 1
  for (int hs = 0; hs < 2; ++hs) {
    const int cb = 2 * q + 128 * hs;
    #pragma unroll
    for (int a = 0; a < 16; ++a) {
      unsigned int d = *reinterpret_cast<unsigned int*>(&S[(g + 16 * a) * 256 + cb]);
      float2 e = __half22float2(u2h(d));
      f[0][a] = e.x; f[1][a] = e.y;
    }
    fwht16(f[0]); fwht16(f[1]);
    #pragma unroll
    for (int a = 0; a < 16; ++a) { f[0][a] *= SC; f[1][a] *= SC; }

    #pragma unroll
    for (int a = 0; a < 16; ++a) {
      const size_t off = (size_t)(g + 16 * a) * 256 + cb;
      float acc0 = 0.f, acc1 = 0.f;
      #pragma unroll
      for (int p = 0; p < 4; ++p) {
        const float2 vv = *reinterpret_cast<const float2*>(v + (size_t)p * NPX + off);
        const float2 tt = *reinterpret_cast<const float2*>(T + (size_t)p * NPX + off);
        acc0 += g_term(f[0][a] * vv.x, fabsf(tt.x));
        acc1 += g_term(f[1][a] * vv.y, fabsf(tt.y));
      }
      f[0][a] = acc0; f[1][a] = acc1;
    }
    fwht16(f[0]); fwht16(f[1]);
    #pragma unroll
    for (int a = 0; a < 16; ++a) { f[0][a] *= SC; f[1][a] *= SC; }
    #pragma unroll
    for (int a = 0; a < 16; ++a) {
      *reinterpret_cast<unsigned int*>(&S[(g + 16 * a) * 256 + cb]) =
          h2u(__floats2half2_rn(f[0][a], f[1][a]));
    }
  }
  __syncthreads();

  // pass C: FWHT16 over k (second half of Rh2; scale already applied)
  #pragma unroll 1
  for (int hs = 0; hs < 2; ++hs) {
    const int cb = 2 * q + 128 * hs;
    #pragma unroll
    for (int k = 0; k < 16; ++k) {
      unsigned int d = *reinterpret_cast<unsigned int*>(&S[(16 * g + k) * 256 + cb]);
      float2 e = __half22float2(u2h(d));
      f[0][k] = e.x; f[1][k] = e.y;
    }
    fwht16(f[0]); fwht16(f[1]);
    #pragma unroll
    for (int k = 0; k < 16; ++k) {
      *reinterpret_cast<unsigned int*>(&S[(16 * g + k) * 256 + cb]) =
          h2u(__floats2half2_rn(f[0][k], f[1][k]));
    }
  }
  __syncthreads();

  // ---- phase 3: row FWHT (x SC) + x residual -> out ----
  #pragma unroll 2
  for (int rr = 0; rr < 16; ++rr) {
    const int row = wv * 16 + rr;
    uint2 pk = *reinterpret_cast<uint2*>(&S[row * 256 + 4 * lane]);
    float2 lo = __half22float2(u2h(pk.x));
    float2 hi = __half22float2(u2h(pk.y));
    float r[4] = {lo.x, lo.y, hi.x, hi.y};
    fwht256_wave(r, lane);
    const float4 xv = *reinterpret_cast<const float4*>(x + pbase + (size_t)row * 256 + 4 * lane);
    float4 o;
    o.x = fmaf(r[0], SC, xv.x);
    o.y = fmaf(r[1], SC, xv.y);
    o.z = fmaf(r[2], SC, xv.z);
    o.w = fmaf(r[3], SC, xv.w);
    *reinterpret_cast<float4*>(out + pbase + (size_t)row * 256 + 4 * lane) = o;
  }
}

extern "C" void kernel_launch(void* const* d_in, const int* in_sizes, int n_in,
                              void* d_out, int out_size, void* d_ws, size_t ws_size,
                              hipStream_t stream) {
  const float* x = (const float*)d_in[0];
  const float* v = (const float*)d_in[1];
  const float* T = (const float*)d_in[2];
  float* out = (float*)d_out;

  k_fused<<<512, 1024, 0, stream>>>(x, v, T, out);
}

// Round 7
// 171.103 us; speedup vs baseline: 1.9427x; 1.3944x over previous
//
#include <hip/hip_runtime.h>
#include <hip/hip_fp16.h>

// WHTConv2D fused single-kernel: out = Rw(Rh(g(Rh(Rw(x))))) + x
//   Rw/Rh = normalized FWHT-256 along w/h (separable; order swapped vs ref, exact)
//   g(f)[h,w] = sum_p tanh(f*v_p) * relu(|f*v_p| - |T_p|)
// x: (8,64,256,256) f32 -> 512 planes of 256x256. One block per plane, whole
// plane staged in LDS as fp16 (128 KB static). v,T: (4,256,256) f32, L2-resident.
//
// Round-7 change: pass B (the only phase with global loads) now runs 4
// quarter-sweeps of ONE column each: f[16]=16 floats live, u16 LDS access
// (2 lanes share a dword per bank = free), scalar coalesced v/T loads,
// unroll-2 a-loop capping in-flight loads. Round-6 still spilled ~210 MB
// because pass B's f[2][16] + 16x8 hoisted v/T loads exceeded the immovable
// 64-VGPR budget. Passes A/C keep the b32 two-half-sweep form (no loads,
// no pressure).

#define NPX 65536   // pixels per plane
#define SC  0.0625f // 1/sqrt(256)

__device__ __forceinline__ unsigned int h2u(__half2 h) {
  union { __half2 h; unsigned int u; } c; c.h = h; return c.u;
}
__device__ __forceinline__ __half2 u2h(unsigned int u) {
  union { __half2 h; unsigned int u; } c; c.u = u; return c.h;
}

// 16-point unnormalized FWHT fully in registers.
__device__ __forceinline__ void fwht16(float f[16]) {
  #pragma unroll
  for (int d = 1; d < 16; d <<= 1) {
    #pragma unroll
    for (int i = 0; i < 16; ++i) {
      if (!(i & d)) {
        float a = f[i], b = f[i | d];
        f[i]     = a + b;
        f[i | d] = a - b;
      }
    }
  }
}

// 256-point unnormalized FWHT across one wave; lane holds elems i = 4*lane + j.
__device__ __forceinline__ void fwht256_wave(float r[4], int lane) {
  float a0 = r[0] + r[1], b0 = r[0] - r[1];
  float a1 = r[2] + r[3], b1 = r[2] - r[3];
  r[0] = a0 + a1; r[1] = b0 + b1; r[2] = a0 - a1; r[3] = b0 - b1;
  #pragma unroll
  for (int m = 1; m <= 32; m <<= 1) {
    const float s = (lane & m) ? -1.0f : 1.0f;
    #pragma unroll
    for (int j = 0; j < 4; ++j) {
      float t = __shfl_xor(r[j], m);
      r[j] = fmaf(r[j], s, t);   // low lane: r+t ; high lane: t-r
    }
  }
}

// one term of g: tanh(a) * relu(|a| - |T|)
__device__ __forceinline__ float g_term(float a, float absT) {
  float ax = fabsf(a);
  float rl = fmaxf(ax - absT, 0.0f);
  float e  = __builtin_amdgcn_exp2f(ax * 2.8853900817779268f); // exp(2ax)
  float th = 1.0f - 2.0f * __builtin_amdgcn_rcpf(e + 1.0f);    // tanh(ax)
  return copysignf(th, a) * rl;
}

__global__ __launch_bounds__(1024) void k_fused(const float* __restrict__ x,
                                                const float* __restrict__ v,
                                                const float* __restrict__ T,
                                                float* __restrict__ out) {
  __shared__ __half S[256 * 256];          // 128 KiB static, pitch 256
  const int tid  = threadIdx.x;
  const int lane = tid & 63;
  const int wv   = tid >> 6;               // wave id 0..15
  const size_t pbase = (size_t)blockIdx.x * NPX;

  // ---- phase 1: row FWHT of x -> LDS (fp16, x SC) ----
  #pragma unroll 2
  for (int rr = 0; rr < 16; ++rr) {
    const int row = wv * 16 + rr;
    const float4 xv = *reinterpret_cast<const float4*>(x + pbase + (size_t)row * 256 + 4 * lane);
    float r[4] = {xv.x, xv.y, xv.z, xv.w};
    fwht256_wave(r, lane);
    uint2 pk;
    pk.x = h2u(__floats2half2_rn(r[0] * SC, r[1] * SC));
    pk.y = h2u(__floats2half2_rn(r[2] * SC, r[3] * SC));
    *reinterpret_cast<uint2*>(&S[row * 256 + 4 * lane]) = pk;
  }
  __syncthreads();

  // ---- phase 2: column Rh o g o Rh, radix-16 (h = 16a + k) ----
  const int q = tid & 63;                  // for passes A/C (column pairs)
  const int g = tid >> 6;                  // wave-uniform row group, passes A/C
  const int c   = tid & 255;               // for pass B (single column)
  const int grp = tid >> 8;                // 0..3, pass B g-subset
  float fp[2][16];

  // pass A: FWHT16 over k (contiguous rows 16g+k); two half-sweeps, b32 LDS
  #pragma unroll 1
  for (int hs = 0; hs < 2; ++hs) {
    const int cb = 2 * q + 128 * hs;
    #pragma unroll
    for (int k = 0; k < 16; ++k) {
      unsigned int d = *reinterpret_cast<unsigned int*>(&S[(16 * g + k) * 256 + cb]);
      float2 e = __half22float2(u2h(d));
      fp[0][k] = e.x; fp[1][k] = e.y;
    }
    fwht16(fp[0]); fwht16(fp[1]);
    #pragma unroll
    for (int k = 0; k < 16; ++k) {
      *reinterpret_cast<unsigned int*>(&S[(16 * g + k) * 256 + cb]) =
          h2u(__floats2half2_rn(fp[0][k], fp[1][k]));
    }
  }
  __syncthreads();

  // pass B: rows gg+16a: FWHT16 over a (completes Rh1) -> xSC -> g -> FWHT16
  // over a (first half of Rh2) -> xSC -> back to LDS.
  // Four quarter-sweeps of ONE column: f[16] live, scalar coalesced v/T loads.
  {
    float f[16];
    #pragma unroll 1
    for (int gg = grp; gg < 16; gg += 4) {
      #pragma unroll
      for (int a = 0; a < 16; ++a)
        f[a] = __half2float(S[(gg + 16 * a) * 256 + c]);
      fwht16(f);
      #pragma unroll
      for (int a = 0; a < 16; ++a) f[a] *= SC;

      #pragma unroll 2
      for (int a = 0; a < 16; ++a) {
        const int off = (gg + 16 * a) * 256 + c;
        float acc = 0.f;
        #pragma unroll
        for (int p = 0; p < 4; ++p)
          acc += g_term(f[a] * v[p * NPX + off], fabsf(T[p * NPX + off]));
        f[a] = acc;
      }

      fwht16(f);
      #pragma unroll
      for (int a = 0; a < 16; ++a)
        S[(gg + 16 * a) * 256 + c] = __float2half_rn(f[a] * SC);
    }
  }
  __syncthreads();

  // pass C: FWHT16 over k (second half of Rh2; scale already applied)
  #pragma unroll 1
  for (int hs = 0; hs < 2; ++hs) {
    const int cb = 2 * q + 128 * hs;
    #pragma unroll
    for (int k = 0; k < 16; ++k) {
      unsigned int d = *reinterpret_cast<unsigned int*>(&S[(16 * g + k) * 256 + cb]);
      float2 e = __half22float2(u2h(d));
      fp[0][k] = e.x; fp[1][k] = e.y;
    }
    fwht16(fp[0]); fwht16(fp[1]);
    #pragma unroll
    for (int k = 0; k < 16; ++k) {
      *reinterpret_cast<unsigned int*>(&S[(16 * g + k) * 256 + cb]) =
          h2u(__floats2half2_rn(fp[0][k], fp[1][k]));
    }
  }
  __syncthreads();

  // ---- phase 3: row FWHT (x SC) + x residual -> out ----
  #pragma unroll 2
  for (int rr = 0; rr < 16; ++rr) {
    const int row = wv * 16 + rr;
    uint2 pk = *reinterpret_cast<uint2*>(&S[row * 256 + 4 * lane]);
    float2 lo = __half22float2(u2h(pk.x));
    float2 hi = __half22float2(u2h(pk.y));
    float r[4] = {lo.x, lo.y, hi.x, hi.y};
    fwht256_wave(r, lane);
    const float4 xv = *reinterpret_cast<const float4*>(x + pbase + (size_t)row * 256 + 4 * lane);
    float4 o;
    o.x = fmaf(r[0], SC, xv.x);
    o.y = fmaf(r[1], SC, xv.y);
    o.z = fmaf(r[2], SC, xv.z);
    o.w = fmaf(r[3], SC, xv.w);
    *reinterpret_cast<float4*>(out + pbase + (size_t)row * 256 + 4 * lane) = o;
  }
}

extern "C" void kernel_launch(void* const* d_in, const int* in_sizes, int n_in,
                              void* d_out, int out_size, void* d_ws, size_t ws_size,
                              hipStream_t stream) {
  const float* x = (const float*)d_in[0];
  const float* v = (const float*)d_in[1];
  const float* T = (const float*)d_in[2];
  float* out = (float*)d_out;

  k_fused<<<512, 1024, 0, stream>>>(x, v, T, out);
}